// Round 1
// 447.898 us; speedup vs baseline: 1.0762x; 1.0762x over previous
//
#include <hip/hip_runtime.h>
#include <math.h>

#define NB 64
#define NS 2048
#define ND 512
#define MTOT (NB * NS)  // 131072
#define CCLIP 10.0f

typedef _Float16 f16x8 __attribute__((ext_vector_type(8)));
typedef _Float16 f16x4 __attribute__((ext_vector_type(4)));
typedef float f32x4 __attribute__((ext_vector_type(4)));

__device__ __forceinline__ void gl2lds16(const void* g, void* l) {
  __builtin_amdgcn_global_load_lds(
      (const __attribute__((address_space(1))) void*)(uintptr_t)g,
      (__attribute__((address_space(3))) void*)(uintptr_t)l, 16, 0, 0);
}

__device__ __forceinline__ float tanh_fast(float x) {
  float e = __expf(2.f * x);
  return 1.f - 2.f * __builtin_amdgcn_rcpf(e + 1.f);
}

// ---------------------------------------------------------------------------
// cvtw: Wref fp32 -> fp16 permuted into the exact LDS-staging order:
//   WhA[((kt*4 + kg)*512 + d)*8 + h] = Wref[d][kt*32 + kg*8 + h]
// ---------------------------------------------------------------------------
__global__ __launch_bounds__(256) void cvtw_kernel(
    const float4* __restrict__ w4, _Float16* __restrict__ WhA) {
  const int idx = blockIdx.x * 256 + threadIdx.x;  // < 65536 float4s
  const int d = idx >> 7;
  const int k = (idx & 127) << 2;
  float4 x = w4[idx];
  f16x4 o;
  o[0] = (_Float16)x.x; o[1] = (_Float16)x.y;
  o[2] = (_Float16)x.z; o[3] = (_Float16)x.w;
  const int kt = k >> 5;
  const int kg = (k >> 3) & 3;
  const int h = k & 7;
  *(f16x4*)(WhA + ((size_t)((kt * 4 + kg) * 512 + d) * 8 + h)) = o;
}

// ---------------------------------------------------------------------------
// qk: q[b,d] = sum_k W_q[d,k] * tgt[b,k]
// ---------------------------------------------------------------------------
__global__ __launch_bounds__(256) void qk_kernel(const float* __restrict__ tgt,
                                                 const float* __restrict__ Wq,
                                                 float* __restrict__ q_ws) {
  const int b = blockIdx.x >> 1;
  const int d = ((blockIdx.x & 1) << 8) + threadIdx.x;
  __shared__ float tl[ND];
  tl[threadIdx.x] = tgt[b * ND + threadIdx.x];
  tl[threadIdx.x + 256] = tgt[b * ND + threadIdx.x + 256];
  __syncthreads();
  const float4* wr = (const float4*)(Wq + (size_t)d * ND);
  float acc = 0.f;
#pragma unroll 8
  for (int k4 = 0; k4 < ND / 4; ++k4) {
    float4 w4 = wr[k4];
    acc += w4.x * tl[4 * k4 + 0] + w4.y * tl[4 * k4 + 1] +
           w4.z * tl[4 * k4 + 2] + w4.w * tl[4 * k4 + 3];
  }
  q_ws[b * ND + d] = acc;
}

// ---------------------------------------------------------------------------
// gemm: block = 64 src rows x FULL N=512, K=512 in 16 kt of 32.
// NEW: 2-phase double-buffered pipeline (T3-minimum): stage kt+1 (B gl2lds +
// A global loads) BEFORE compute of kt; A cvt+ds_write after the MFMAs;
// single __syncthreads per kt. vmcnt(0) drain now hides under ~350cyc of
// ds_read+MFMA issue instead of being fully exposed.
// NEW: fused d' partial: w for the block's 64 rows is known here (no softmax
// max needed: logit<=C), so accumulate dp_part[d] = sum_r w_r*src[r][d] from
// L2-hot src and write per-block partials. dp_kernel deleted.
// LDS: sA 2x4 KB + sB 2x32 KB + ured 1 KB + wsh 256 B = 73.25 KB -> 2 blk/CU.
// ---------------------------------------------------------------------------
__global__ __launch_bounds__(256, 2) void gemm_kernel(
    const float* __restrict__ src, const _Float16* __restrict__ WhA,
    const float* __restrict__ q_ws, const float* __restrict__ v,
    float* __restrict__ out_logit, float* __restrict__ out_probs_w,
    float* __restrict__ dp_ws) {
  __shared__ __align__(16) _Float16 sA[2][4 * 64 * 8];   // 2 x 4 KB
  __shared__ __align__(16) _Float16 sB[2][4 * 512 * 8];  // 2 x 32 KB
  __shared__ float ured[4 * 64];                         // 1 KB
  __shared__ float wsh[64];                              // 256 B

  const int tid = threadIdx.x;
  const int lane = tid & 63;
  const int w = tid >> 6;       // col-quarter 0..3
  const int s0 = blockIdx.x << 6;
  const int bb = blockIdx.x >> 5;

  const int quad = lane >> 4;
  const int l15 = lane & 15;

  // A staging mapping: (row = tid>>2, kg = tid&3) -> 4 consecutive lanes
  // cover one row's 128 B per kt (128-B HBM granularity, was 32-B).
  const int ar = tid >> 2;
  const int akg = tid & 3;
  const float4* ap =
      (const float4*)(src + ((size_t)(s0 + ar) << 9)) + akg * 2;
  const int aoff = (akg * 64 + ar) * 8;

  const char* gB = (const char*)WhA;

  f32x4 acc[4][8];
#pragma unroll
  for (int i = 0; i < 4; ++i)
#pragma unroll
    for (int j = 0; j < 8; ++j) acc[i][j] = (f32x4){0.f, 0.f, 0.f, 0.f};

  // ---- prologue: stage kt=0 into buf 0
#pragma unroll
  for (int i = 0; i < 8; ++i) {
    const int c = w * 8 + i;
    gl2lds16(gB + c * 1024 + lane * 16, (char*)&sB[0][0] + c * 1024);
  }
  {
    float4 x0 = ap[0];
    float4 x1 = ap[1];
    f16x8 h;
    h[0] = (_Float16)x0.x; h[1] = (_Float16)x0.y;
    h[2] = (_Float16)x0.z; h[3] = (_Float16)x0.w;
    h[4] = (_Float16)x1.x; h[5] = (_Float16)x1.y;
    h[6] = (_Float16)x1.z; h[7] = (_Float16)x1.w;
    *(f16x8*)(&sA[0][0] + aoff) = h;
  }
  __syncthreads();

  int buf = 0;
  for (int kt = 0; kt < 16; ++kt) {
    const int nb = buf ^ 1;
    float4 x0, x1;
    // stage kt+1 into buf^1: issue loads FIRST (latency hides under compute)
    if (kt < 15) {
#pragma unroll
      for (int i = 0; i < 8; ++i) {
        const int c = w * 8 + i;
        gl2lds16(gB + (size_t)(kt + 1) * 32768 + c * 1024 + lane * 16,
                 (char*)&sB[nb][0] + c * 1024);
      }
      x0 = ap[(kt + 1) * 8];
      x1 = ap[(kt + 1) * 8 + 1];
    }
    // compute kt from buf
    f16x8 af[4], bf[8];
#pragma unroll
    for (int i = 0; i < 4; ++i)
      af[i] = *(const f16x8*)(&sA[buf][0] + (quad * 64 + 16 * i + l15) * 8);
#pragma unroll
    for (int j = 0; j < 8; ++j)
      bf[j] = *(const f16x8*)(&sB[buf][0] +
                              (quad * 512 + w * 128 + 16 * j + l15) * 8);
#pragma unroll
    for (int i = 0; i < 4; ++i)
#pragma unroll
      for (int j = 0; j < 8; ++j)
        acc[i][j] = __builtin_amdgcn_mfma_f32_16x16x32_f16(af[i], bf[j],
                                                           acc[i][j], 0, 0, 0);
    // A convert + ds_write late (vmcnt wait for x0/x1 lands after MFMA issue)
    if (kt < 15) {
      f16x8 h;
      h[0] = (_Float16)x0.x; h[1] = (_Float16)x0.y;
      h[2] = (_Float16)x0.z; h[3] = (_Float16)x0.w;
      h[4] = (_Float16)x1.x; h[5] = (_Float16)x1.y;
      h[6] = (_Float16)x1.z; h[7] = (_Float16)x1.w;
      *(f16x8*)(&sA[nb][0] + aoff) = h;
    }
    __syncthreads();
    buf = nb;
  }

  // epilogue: pu[row] = sum over this wave's 128 cols of tanh(C+q)*v
  float pu[4][4];
#pragma unroll
  for (int i = 0; i < 4; ++i)
#pragma unroll
    for (int r = 0; r < 4; ++r) pu[i][r] = 0.f;

#pragma unroll
  for (int j = 0; j < 8; ++j) {
    const int dl = w * 128 + 16 * j + l15;
    const float qq = q_ws[bb * ND + dl];
    const float vv = v[dl];
#pragma unroll
    for (int i = 0; i < 4; ++i) {
      f32x4 a = acc[i][j];
#pragma unroll
      for (int r = 0; r < 4; ++r) pu[i][r] += tanh_fast(a[r] + qq) * vv;
    }
  }

#pragma unroll
  for (int i = 0; i < 4; ++i)
#pragma unroll
    for (int r = 0; r < 4; ++r) {
      float x = pu[i][r];
      x += __shfl_xor(x, 1, 16);
      x += __shfl_xor(x, 2, 16);
      x += __shfl_xor(x, 4, 16);
      x += __shfl_xor(x, 8, 16);
      pu[i][r] = x;
    }

  if (l15 == 0) {
#pragma unroll
    for (int i = 0; i < 4; ++i)
#pragma unroll
      for (int r = 0; r < 4; ++r)
        ured[w * 64 + 16 * i + quad * 4 + r] = pu[i][r];
  }
  __syncthreads();
  if (tid < 64) {
    const float u =
        ured[tid] + ured[64 + tid] + ured[128 + tid] + ured[192 + tid];
    const float lg = CCLIP * tanhf(u);
    out_logit[s0 + tid] = lg;
    const float wexp = expf(lg - CCLIP);
    out_probs_w[s0 + tid] = wexp;
    wsh[tid] = wexp;
  }
  __syncthreads();

  // fused d' partial: dp_part[d] = sum_{r=0..63} w_r * src[s0+r][d]
  // src slice (128 KB) was just streamed by this block -> L2/L3-hot.
  const int c4 = tid & 127;   // float4 column index (0..127)
  const int half = tid >> 7;  // row half 0/1
  const float4* sp = (const float4*)(src + ((size_t)s0 << 9)) + c4;
  float dx = 0.f, dy = 0.f, dz = 0.f, dw = 0.f;
  const int r0 = half << 5;
#pragma unroll 4
  for (int r = r0; r < r0 + 32; ++r) {
    const float wr = wsh[r];
    const float4 x = sp[(size_t)r * 128];
    dx += wr * x.x; dy += wr * x.y; dz += wr * x.z; dw += wr * x.w;
  }
  // combine the two row-halves via LDS (reuse sA as scratch, 4 KB needed)
  float4* red4 = (float4*)&sA[0][0];
  if (half) {
    float4 o; o.x = dx; o.y = dy; o.z = dz; o.w = dw;
    red4[c4] = o;
  }
  __syncthreads();
  if (!half) {
    float4 o = red4[c4];
    o.x += dx; o.y += dy; o.z += dz; o.w += dw;
    *(float4*)(dp_ws + (size_t)blockIdx.x * ND + (c4 << 2)) = o;
  }
}

// ---------------------------------------------------------------------------
// fin: per b: S = sum w (parked in out_probs); probs *= 1/S;
//      d'[d] = (sum of 32 per-block partials)/S
// ---------------------------------------------------------------------------
__global__ __launch_bounds__(256) void fin_kernel(
    const float* __restrict__ dp_ws, float* __restrict__ out_dp,
    float* __restrict__ out_probs) {
  const int b = blockIdx.x;
  const int tid = threadIdx.x;
  __shared__ float red[4];
  __shared__ float s_inv;

  float x = 0.f;
  for (int idx = tid; idx < NS; idx += 256) x += out_probs[b * NS + idx];
#pragma unroll
  for (int m = 32; m; m >>= 1) x += __shfl_xor(x, m, 64);
  if ((tid & 63) == 0) red[tid >> 6] = x;
  __syncthreads();
  if (tid == 0) s_inv = 1.f / (red[0] + red[1] + red[2] + red[3]);
  __syncthreads();
  const float inv = s_inv;

  for (int idx = tid; idx < NS; idx += 256)
    out_probs[b * NS + idx] *= inv;

  for (int d = tid; d < ND; d += 256) {
    float acc = 0.f;
#pragma unroll 8
    for (int ch = 0; ch < 32; ++ch)
      acc += dp_ws[(size_t)(b * 32 + ch) * ND + d];
    out_dp[b * ND + d] = acc * inv;
  }
}

// ---------------------------------------------------------------------------
extern "C" void kernel_launch(void* const* d_in, const int* in_sizes, int n_in,
                              void* d_out, int out_size, void* d_ws,
                              size_t ws_size, hipStream_t stream) {
  const float* src = (const float*)d_in[0];   // [64,2048,512]
  const float* tgt = (const float*)d_in[1];   // [64,1,512]
  const float* Wq = (const float*)d_in[2];    // [512,512]
  const float* Wref = (const float*)d_in[3];  // [512,512]
  const float* v = (const float*)d_in[4];     // [512]

  float* out = (float*)d_out;
  float* out_dp = out;                        // 64*512
  float* out_probs = out + NB * ND;           // 64*2048 (holds w pre-fin)
  float* out_logit = out + NB * ND + NB * NS; // 64*2048

  // workspace: 524288 + 131072 + 4194304 = 4,849,664 B (proven footprint)
  char* ws = (char*)d_ws;
  _Float16* WhA = (_Float16*)ws;              // 512*512*2 =   524,288 B
  float* q_ws = (float*)(ws + 524288);        // 64*512*4  =   131,072 B
  float* dp_ws = (float*)(ws + 655360);       // 2048*512*4 = 4,194,304 B

  cvtw_kernel<<<256, 256, 0, stream>>>((const float4*)Wref, WhA);
  qk_kernel<<<2 * NB, 256, 0, stream>>>(tgt, Wq, q_ws);
  gemm_kernel<<<MTOT / 64, 256, 0, stream>>>(src, WhA, q_ws, v, out_logit,
                                             out_probs, dp_ws);
  fin_kernel<<<NB, 256, 0, stream>>>(dp_ws, out_dp, out_probs);
}

// Round 5
// 441.445 us; speedup vs baseline: 1.0919x; 1.0146x over previous
//
#include <hip/hip_runtime.h>
#include <math.h>

#define NB 64
#define NS 2048
#define ND 512
#define MTOT (NB * NS)  // 131072
#define CCLIP 10.0f

typedef _Float16 f16x8 __attribute__((ext_vector_type(8)));
typedef _Float16 f16x4 __attribute__((ext_vector_type(4)));
typedef float f32x4 __attribute__((ext_vector_type(4)));

__device__ __forceinline__ void gl2lds16(const void* g, void* l) {
  __builtin_amdgcn_global_load_lds(
      (const __attribute__((address_space(1))) void*)(uintptr_t)g,
      (__attribute__((address_space(3))) void*)(uintptr_t)l, 16, 0, 0);
}

__device__ __forceinline__ float tanh_fast(float x) {
  float e = __expf(2.f * x);
  return 1.f - 2.f * __builtin_amdgcn_rcpf(e + 1.f);
}

// ---------------------------------------------------------------------------
// cvtw: Wref fp32 -> fp16 permuted into the exact LDS-staging order:
//   WhA[((kt*4 + kg)*512 + d)*8 + h] = Wref[d][kt*32 + kg*8 + h]
// ---------------------------------------------------------------------------
__global__ __launch_bounds__(256) void cvtw_kernel(
    const float4* __restrict__ w4, _Float16* __restrict__ WhA) {
  const int idx = blockIdx.x * 256 + threadIdx.x;  // < 65536 float4s
  const int d = idx >> 7;
  const int k = (idx & 127) << 2;
  float4 x = w4[idx];
  f16x4 o;
  o[0] = (_Float16)x.x; o[1] = (_Float16)x.y;
  o[2] = (_Float16)x.z; o[3] = (_Float16)x.w;
  const int kt = k >> 5;
  const int kg = (k >> 3) & 3;
  const int h = k & 7;
  *(f16x4*)(WhA + ((size_t)((kt * 4 + kg) * 512 + d) * 8 + h)) = o;
}

// ---------------------------------------------------------------------------
// qk: q[b,d] = sum_k W_q[d,k] * tgt[b,k]
// ---------------------------------------------------------------------------
__global__ __launch_bounds__(256) void qk_kernel(const float* __restrict__ tgt,
                                                 const float* __restrict__ Wq,
                                                 float* __restrict__ q_ws) {
  const int b = blockIdx.x >> 1;
  const int d = ((blockIdx.x & 1) << 8) + threadIdx.x;
  __shared__ float tl[ND];
  tl[threadIdx.x] = tgt[b * ND + threadIdx.x];
  tl[threadIdx.x + 256] = tgt[b * ND + threadIdx.x + 256];
  __syncthreads();
  const float4* wr = (const float4*)(Wq + (size_t)d * ND);
  float acc = 0.f;
#pragma unroll 8
  for (int k4 = 0; k4 < ND / 4; ++k4) {
    float4 w4 = wr[k4];
    acc += w4.x * tl[4 * k4 + 0] + w4.y * tl[4 * k4 + 1] +
           w4.z * tl[4 * k4 + 2] + w4.w * tl[4 * k4 + 3];
  }
  q_ws[b * ND + d] = acc;
}

// ---------------------------------------------------------------------------
// gemm: block = 128 src rows x FULL N=512, K=512 in 16 kt of 32.
// 512 threads / 8 waves; wave (h=w>>2, cq=w&3) owns rows h*64..+63, cols
// cq*128..+127 -> acc[4][8] f32x4 per wave.
// 2-deep pipeline: triple-buffer sB (3x32K), double sA (2x8K); stage tile
// kt+2 during kt via gl2lds.
// Loop-wait safety (issue-order INDEPENDENT): each iter issues exactly 6
// VMEM ops between sched_barrier(0) fences, so s_waitcnt vmcnt(6) at the
// fence retires everything from prior iters (incl. G(kt+1)).
// PROLOGUE FIX (round-2 bug): the old vmcnt(6) assumed program-order issue
// [G0x4, A1x2, G1x4]; the scheduler may hoist the A1 dwordx4 loads above
// the gl2lds group, leaving half of G0 unretired at the barrier -> sB0
// partially garbage -> logit errors. Full vmcnt(0) drain here (one-time,
// ~500 cyc/block) is order-proof.
// sA XOR swizzle (row ^ (kg<<2)) kills the 4-way ds_write conflict.
// Fused d' partial kept (w known in-block; src slice L2-hot).
// LDS: 96 + 16 + 2 + 0.5 = 114.5 KB -> 1 block/CU, 8 waves (2/SIMD).
// ---------------------------------------------------------------------------
__global__ __launch_bounds__(512, 2) void gemm_kernel(
    const float* __restrict__ src, const _Float16* __restrict__ WhA,
    const float* __restrict__ q_ws, const float* __restrict__ v,
    float* __restrict__ out_logit, float* __restrict__ out_probs_w,
    float* __restrict__ dp_ws) {
  __shared__ __align__(16) _Float16 sBall[3 * 16384];  // 96 KB
  __shared__ __align__(16) _Float16 sAall[2 * 4096];   // 16 KB
  __shared__ float ured[4 * 128];                      // 2 KB
  __shared__ float wsh[128];                           // 512 B

  const int tid = threadIdx.x;
  const int lane = tid & 63;
  const int w = tid >> 6;      // 0..7
  const int h = w >> 2;        // row half
  const int cq = w & 3;        // col quarter
  const int s0 = blockIdx.x << 7;
  const int bb = blockIdx.x >> 4;

  const int quad = lane >> 4;
  const int l15 = lane & 15;

  // A staging: 4 consecutive lanes cover one row's 128 B (contiguous)
  const int ar = tid >> 2;   // 0..127
  const int akg = tid & 3;
  const float4* ap =
      (const float4*)(src + ((size_t)(s0 + ar) << 9)) + akg * 2;
  const int aoff = akg * 1024 + ((ar ^ (akg << 2)) << 3);  // swizzled f16 idx

  const char* gB = (const char*)WhA;

  f32x4 acc[4][8];
#pragma unroll
  for (int i = 0; i < 4; ++i)
#pragma unroll
    for (int j = 0; j < 8; ++j) acc[i][j] = (f32x4){0.f, 0.f, 0.f, 0.f};

  // ---- prologue: A(0)->sA[0], G(0)->sB0; A(1)->regs, G(1)->sB1
  float4 x0 = ap[0];
  float4 x1 = ap[1];
  {
    f16x8 hh;
    hh[0] = (_Float16)x0.x; hh[1] = (_Float16)x0.y;
    hh[2] = (_Float16)x0.z; hh[3] = (_Float16)x0.w;
    hh[4] = (_Float16)x1.x; hh[5] = (_Float16)x1.y;
    hh[6] = (_Float16)x1.z; hh[7] = (_Float16)x1.w;
    *(f16x8*)(sAall + aoff) = hh;
  }
#pragma unroll
  for (int i = 0; i < 4; ++i) {
    const int c = w * 4 + i;
    gl2lds16(gB + c * 1024 + lane * 16, (char*)sBall + c * 1024);
  }
  x0 = ap[8];
  x1 = ap[9];
#pragma unroll
  for (int i = 0; i < 4; ++i) {
    const int c = w * 4 + i;
    gl2lds16(gB + 32768 + c * 1024 + lane * 16,
             (char*)(sBall + 16384) + c * 1024);
  }
  __builtin_amdgcn_sched_barrier(0);
  // Full drain: order-proof (see header comment). One-time cost per block.
  asm volatile("s_waitcnt vmcnt(0)" ::: "memory");
  asm volatile("s_waitcnt lgkmcnt(0)" ::: "memory");
  __builtin_amdgcn_s_barrier();
  __builtin_amdgcn_sched_barrier(0);

  for (int kt = 0; kt < 16; ++kt) {
    const _Float16* sB = sBall + (kt % 3) * 16384;
    const _Float16* sA = sAall + (kt & 1) * 4096;

    f16x8 af[4], bf[8];
#pragma unroll
    for (int i = 0; i < 4; ++i) {
      const int row = h * 64 + 16 * i + l15;
      af[i] = *(const f16x8*)(sA + quad * 1024 + ((row ^ (quad << 2)) << 3));
    }
#pragma unroll
    for (int j = 0; j < 8; ++j)
      bf[j] = *(const f16x8*)(sB +
                              ((quad * 512 + cq * 128 + 16 * j + l15) << 3));

    // cvt x (=A(kt+1)) -> sA[(kt+1)&1]
    if (kt < 15) {
      f16x8 hh;
      hh[0] = (_Float16)x0.x; hh[1] = (_Float16)x0.y;
      hh[2] = (_Float16)x0.z; hh[3] = (_Float16)x0.w;
      hh[4] = (_Float16)x1.x; hh[5] = (_Float16)x1.y;
      hh[6] = (_Float16)x1.z; hh[7] = (_Float16)x1.w;
      *(f16x8*)(sAall + ((kt + 1) & 1) * 4096 + aoff) = hh;
    }
    // issue kt+2 staging (A to regs, B via gl2lds) -- stays in flight
    // across the barrier (counted vmcnt below never drains it)
    if (kt < 14) {
      x0 = ap[(kt + 2) * 8];
      x1 = ap[(kt + 2) * 8 + 1];
      char* sBn = (char*)(sBall + ((kt + 2) % 3) * 16384);
#pragma unroll
      for (int i = 0; i < 4; ++i) {
        const int c = w * 4 + i;
        gl2lds16(gB + (size_t)(kt + 2) * 32768 + c * 1024 + lane * 16,
                 sBn + c * 1024);
      }
    }

#pragma unroll
    for (int i = 0; i < 4; ++i)
#pragma unroll
      for (int j = 0; j < 8; ++j)
        acc[i][j] = __builtin_amdgcn_mfma_f32_16x16x32_f16(af[i], bf[j],
                                                           acc[i][j], 0, 0, 0);

    __builtin_amdgcn_sched_barrier(0);
    if (kt < 14) {
      // exactly 6 VMEM issued this iter -> vmcnt(6) retires all prior iters'
      asm volatile("s_waitcnt vmcnt(6)" ::: "memory");
    } else {
      asm volatile("s_waitcnt vmcnt(0)" ::: "memory");  // drain tail
    }
    asm volatile("s_waitcnt lgkmcnt(0)" ::: "memory");
    __builtin_amdgcn_s_barrier();
    __builtin_amdgcn_sched_barrier(0);
  }

  // epilogue: pu[row] = sum over this wave's 128 cols of tanh(.+q)*v
  float pu[4][4];
#pragma unroll
  for (int i = 0; i < 4; ++i)
#pragma unroll
    for (int r = 0; r < 4; ++r) pu[i][r] = 0.f;

#pragma unroll
  for (int j = 0; j < 8; ++j) {
    const int dl = cq * 128 + 16 * j + l15;
    const float qq = q_ws[bb * ND + dl];
    const float vv = v[dl];
#pragma unroll
    for (int i = 0; i < 4; ++i) {
      f32x4 a = acc[i][j];
#pragma unroll
      for (int r = 0; r < 4; ++r) pu[i][r] += tanh_fast(a[r] + qq) * vv;
    }
  }

#pragma unroll
  for (int i = 0; i < 4; ++i)
#pragma unroll
    for (int r = 0; r < 4; ++r) {
      float x = pu[i][r];
      x += __shfl_xor(x, 1, 16);
      x += __shfl_xor(x, 2, 16);
      x += __shfl_xor(x, 4, 16);
      x += __shfl_xor(x, 8, 16);
      pu[i][r] = x;
    }

  if (l15 == 0) {
#pragma unroll
    for (int i = 0; i < 4; ++i)
#pragma unroll
      for (int r = 0; r < 4; ++r)
        ured[cq * 128 + h * 64 + 16 * i + quad * 4 + r] = pu[i][r];
  }
  __syncthreads();
  if (tid < 128) {
    const float u =
        ured[tid] + ured[128 + tid] + ured[256 + tid] + ured[384 + tid];
    const float lg = CCLIP * tanhf(u);
    out_logit[s0 + tid] = lg;
    const float wexp = expf(lg - CCLIP);
    out_probs_w[s0 + tid] = wexp;
    wsh[tid] = wexp;
  }
  __syncthreads();

  // fused d' partial: dp_part[d] = sum_{r=0..127} w_r * src[s0+r][d]
  const int c4 = tid & 127;    // float4 column index (0..127)
  const int part = tid >> 7;   // row quarter 0..3
  const float4* sp = (const float4*)(src + ((size_t)s0 << 9)) + c4;
  float dx = 0.f, dy = 0.f, dz = 0.f, dw = 0.f;
  const int r0 = part << 5;
#pragma unroll 4
  for (int r = r0; r < r0 + 32; ++r) {
    const float wr = wsh[r];
    const float4 x = sp[(size_t)r * 128];
    dx += wr * x.x; dy += wr * x.y; dz += wr * x.z; dw += wr * x.w;
  }
  // combine 4 row-quarters via LDS (alias onto sBall, 8 KB)
  float4* red4 = (float4*)sBall;
  {
    float4 o; o.x = dx; o.y = dy; o.z = dz; o.w = dw;
    red4[part * 128 + c4] = o;
  }
  __syncthreads();
  if (tid < 128) {
    float4 a0 = red4[c4];
    float4 a1 = red4[128 + c4];
    float4 a2 = red4[256 + c4];
    float4 a3 = red4[384 + c4];
    float4 o;
    o.x = a0.x + a1.x + a2.x + a3.x;
    o.y = a0.y + a1.y + a2.y + a3.y;
    o.z = a0.z + a1.z + a2.z + a3.z;
    o.w = a0.w + a1.w + a2.w + a3.w;
    *(float4*)(dp_ws + (size_t)blockIdx.x * ND + (c4 << 2)) = o;
  }
}

// ---------------------------------------------------------------------------
// fin: per b: S = sum w (parked in out_probs); probs *= 1/S;
//      d'[d] = (sum of 16 per-block partials)/S
// ---------------------------------------------------------------------------
__global__ __launch_bounds__(256) void fin_kernel(
    const float* __restrict__ dp_ws, float* __restrict__ out_dp,
    float* __restrict__ out_probs) {
  const int b = blockIdx.x;
  const int tid = threadIdx.x;
  __shared__ float red[4];
  __shared__ float s_inv;

  float x = 0.f;
  for (int idx = tid; idx < NS; idx += 256) x += out_probs[b * NS + idx];
#pragma unroll
  for (int m = 32; m; m >>= 1) x += __shfl_xor(x, m, 64);
  if ((tid & 63) == 0) red[tid >> 6] = x;
  __syncthreads();
  if (tid == 0) s_inv = 1.f / (red[0] + red[1] + red[2] + red[3]);
  __syncthreads();
  const float inv = s_inv;

  for (int idx = tid; idx < NS; idx += 256)
    out_probs[b * NS + idx] *= inv;

  for (int d = tid; d < ND; d += 256) {
    float acc = 0.f;
#pragma unroll
    for (int ch = 0; ch < 16; ++ch)
      acc += dp_ws[(size_t)(b * 16 + ch) * ND + d];
    out_dp[b * ND + d] = acc * inv;
  }
}

// ---------------------------------------------------------------------------
extern "C" void kernel_launch(void* const* d_in, const int* in_sizes, int n_in,
                              void* d_out, int out_size, void* d_ws,
                              size_t ws_size, hipStream_t stream) {
  const float* src = (const float*)d_in[0];   // [64,2048,512]
  const float* tgt = (const float*)d_in[1];   // [64,1,512]
  const float* Wq = (const float*)d_in[2];    // [512,512]
  const float* Wref = (const float*)d_in[3];  // [512,512]
  const float* v = (const float*)d_in[4];     // [512]

  float* out = (float*)d_out;
  float* out_dp = out;                        // 64*512
  float* out_probs = out + NB * ND;           // 64*2048 (holds w pre-fin)
  float* out_logit = out + NB * ND + NB * NS; // 64*2048

  // workspace: 524288 + 131072 + 2097152 = 2,752,512 B
  char* ws = (char*)d_ws;
  _Float16* WhA = (_Float16*)ws;              // 512*512*2 =   524,288 B
  float* q_ws = (float*)(ws + 524288);        // 64*512*4  =   131,072 B
  float* dp_ws = (float*)(ws + 655360);       // 1024*512*4 = 2,097,152 B

  cvtw_kernel<<<256, 256, 0, stream>>>((const float4*)Wref, WhA);
  qk_kernel<<<2 * NB, 256, 0, stream>>>(tgt, Wq, q_ws);
  gemm_kernel<<<MTOT / 128, 512, 0, stream>>>(src, WhA, q_ws, v, out_logit,
                                              out_probs, dp_ws);
  fin_kernel<<<NB, 256, 0, stream>>>(dp_ws, out_dp, out_probs);
}